// Round 3
// baseline (236.881 us; speedup 1.0000x reference)
//
#include <hip/hip_runtime.h>

// Destroy operator: y = (U kron I2) @ x where U[i,i+1] = sqrt(i+1).
// Reduces to: out[r, :] = sqrt(r/2 + 1) * x[r+2, :] for r < 2D-2; last 2 rows = 0.
// x: (2D, B) fp32 row-major, D = 4096, B = 4096.
//
// R6: single-variable experiment vs R5 — CACHED loads (drop __builtin_
// nontemporal_load), keep NT stores. R5's 16-deep MLP was neutral vs R4
// (217.4 -> 219.9 us), killing the "shallow MLP" theory. Kernel slice
// (~58 us for 268 MB = 4.6 TB/s) trails both the 6.3 TB/s cached-copy
// ceiling and the fills' 6.7 TB/s pure-write rate; the remaining structural
// difference vs the copy benchmark is the nt flag on loads (L2-bypass read
// path). NT stores stay: zero output reuse, and keeping the output stream
// out of the LLC gives the re-read input a chance at Infinity Cache
// residency across timing iterations.
//
// Zero tail (pair D-1): coefficient 0, source clamped in-bounds — no
// divergence, no OOB reads.

typedef float vf4 __attribute__((ext_vector_type(4)));

constexpr int kD = 4096;
constexpr int kB = 4096;
constexpr int kV4Row  = kB / 4;        // 1024 float4 per row
constexpr int kV4Pair = 2 * kV4Row;    // 2048 float4 per row-pair
constexpr int kPT     = 8;             // float4 per thread per row-pair (2048/256)

__global__ __launch_bounds__(256) void destroy_kernel(
    const vf4* __restrict__ x, vf4* __restrict__ y) {
    const int t  = threadIdx.x;
    const int pA = blockIdx.x * 2;     // row-pair indices: pA, pA+1
    const int pB = pA + 1;

    const int baseA = pA * kV4Pair + t;
    const int baseB = pB * kV4Pair + t;

    // Last row-pair writes zeros: coefficient 0, source clamped in-bounds.
    const bool  lastB = (pB == kD - 1);
    const float cA = sqrtf((float)(pA + 1));
    const float cB = lastB ? 0.f : sqrtf((float)(pB + 1));
    const int   srcB = lastB ? baseB : (baseB + kV4Pair);

    vf4 va[kPT], vb[kPT];
#pragma unroll
    for (int j = 0; j < kPT; ++j)
        va[j] = x[baseA + kV4Pair + j * 256];   // cached loads (R6 change)
#pragma unroll
    for (int j = 0; j < kPT; ++j)
        vb[j] = x[srcB + j * 256];

#pragma unroll
    for (int j = 0; j < kPT; ++j)
        __builtin_nontemporal_store(cA * va[j], &y[baseA + j * 256]);
#pragma unroll
    for (int j = 0; j < kPT; ++j)
        __builtin_nontemporal_store(cB * vb[j], &y[baseB + j * 256]);
}

extern "C" void kernel_launch(void* const* d_in, const int* in_sizes, int n_in,
                              void* d_out, int out_size, void* d_ws, size_t ws_size,
                              hipStream_t stream) {
    const vf4* x = (const vf4*)d_in[0];
    vf4* y = (vf4*)d_out;
    destroy_kernel<<<dim3(kD / 2), dim3(256), 0, stream>>>(x, y);
}

// Round 4
// 232.785 us; speedup vs baseline: 1.0176x; 1.0176x over previous
//
#include <hip/hip_runtime.h>

// Destroy operator: y = (U kron I2) @ x where U[i,i+1] = sqrt(i+1).
// Reduces to: out[r, :] = sqrt(r/2 + 1) * x[r+2, :] for r < 2D-2; last 2 rows = 0.
// x: (2D, B) fp32 row-major, D = 4096, B = 4096.
//
// R7: single-variable experiment vs R6 — PLAIN (cached) stores. Full 2x2 map:
//   nt-load + nt-store     : ~68 us inferred (R5)  ~3.9 TB/s
//   cached-load + nt-store : ~85 us measured (R6)  ~3.1 TB/s  <- regression
//   cached + cached        : THIS — the m13 copy config (6.29 TB/s) and the
//                            rocclr fill config (6.7 TB/s pure write).
// Every NT-store config underperforms; theory is the no-allocate write path
// is the throttle on gfx950, and "cache pollution" was a phantom fear (the
// 256 MiB LLC is memory-side; fills stream through it at full rate). R6 also
// proved the input gets L3 read-hits across iterations (FETCH 128->64 MiB),
// which cached loads preserve.
//
// Zero tail (pair D-1): coefficient 0, source clamped in-bounds — no
// divergence, no OOB reads.

typedef float vf4 __attribute__((ext_vector_type(4)));

constexpr int kD = 4096;
constexpr int kB = 4096;
constexpr int kV4Row  = kB / 4;        // 1024 float4 per row
constexpr int kV4Pair = 2 * kV4Row;    // 2048 float4 per row-pair
constexpr int kPT     = 8;             // float4 per thread per row-pair (2048/256)

__global__ __launch_bounds__(256) void destroy_kernel(
    const vf4* __restrict__ x, vf4* __restrict__ y) {
    const int t  = threadIdx.x;
    const int pA = blockIdx.x * 2;     // row-pair indices: pA, pA+1
    const int pB = pA + 1;

    const int baseA = pA * kV4Pair + t;
    const int baseB = pB * kV4Pair + t;

    // Last row-pair writes zeros: coefficient 0, source clamped in-bounds.
    const bool  lastB = (pB == kD - 1);
    const float cA = sqrtf((float)(pA + 1));
    const float cB = lastB ? 0.f : sqrtf((float)(pB + 1));
    const int   srcB = lastB ? baseB : (baseB + kV4Pair);

    vf4 va[kPT], vb[kPT];
#pragma unroll
    for (int j = 0; j < kPT; ++j)
        va[j] = x[baseA + kV4Pair + j * 256];
#pragma unroll
    for (int j = 0; j < kPT; ++j)
        vb[j] = x[srcB + j * 256];

#pragma unroll
    for (int j = 0; j < kPT; ++j)
        y[baseA + j * 256] = cA * va[j];       // cached stores (R7 change)
#pragma unroll
    for (int j = 0; j < kPT; ++j)
        y[baseB + j * 256] = cB * vb[j];
}

extern "C" void kernel_launch(void* const* d_in, const int* in_sizes, int n_in,
                              void* d_out, int out_size, void* d_ws, size_t ws_size,
                              hipStream_t stream) {
    const vf4* x = (const vf4*)d_in[0];
    vf4* y = (vf4*)d_out;
    destroy_kernel<<<dim3(kD / 2), dim3(256), 0, stream>>>(x, y);
}

// Round 5
// 218.238 us; speedup vs baseline: 1.0854x; 1.0667x over previous
//
#include <hip/hip_runtime.h>

// Destroy operator: y = (U kron I2) @ x where U[i,i+1] = sqrt(i+1).
// Reduces to: out[r, :] = sqrt(r/2 + 1) * x[r+2, :] for r < 2D-2; last 2 rows = 0.
// x: (2D, B) fp32 row-major, D = 4096, B = 4096.
//
// R8: grid-stride software pipeline, nt/nt (the winning hint config from the
// R4-R7 2x2: nt/nt 217-220 us, any cached variant 233-237 us).
// Theory: the one-shot all-resident structure phase-locks the machine --
// ~20 us pure-read phase, global turnaround, ~20 us pure-write phase, plus
// latency/tail exposure => ~55 us kernel slice vs ~43 us steady-state-mixed
// ideal (6.3 TB/s copy ceiling). This version: 1024 blocks (4/CU), each owns
// 4 row-pairs at stride 1024, double-buffered a/b so loads for the next pair
// are always in flight while the previous pair's stores drain:
//   LD(a,p0) LD(b,p1) ST(a,p0) LD(a,p2) ST(b,p1) LD(b,p3) ST(a,p2) ST(b,p3)
//
// Zero tail (pair D-1, only reachable as p3): coefficient 0, source clamped
// in-bounds -- no divergence, no OOB reads.

typedef float vf4 __attribute__((ext_vector_type(4)));

constexpr int kD = 4096;
constexpr int kB = 4096;
constexpr int kV4Row  = kB / 4;        // 1024 float4 per row
constexpr int kV4Pair = 2 * kV4Row;    // 2048 float4 per row-pair
constexpr int kPT     = 8;             // float4 per thread per row-pair (2048/256)
constexpr int kBlocks = 1024;          // 4 row-pairs per block, stride 1024

__global__ __launch_bounds__(256) void destroy_kernel(
    const vf4* __restrict__ x, vf4* __restrict__ y) {
    const int t = threadIdx.x;

    const int p0 = blockIdx.x;
    const int p1 = p0 + kBlocks;
    const int p2 = p0 + 2 * kBlocks;
    const int p3 = p0 + 3 * kBlocks;   // may be kD-1 (zero tail)

    // Source base (clamped for zero tail), dest base, coefficient per pair.
    const int  s0 = (p0 + 1) * kV4Pair + t;
    const int  s1 = (p1 + 1) * kV4Pair + t;
    const int  s2 = (p2 + 1) * kV4Pair + t;
    const bool last3 = (p3 == kD - 1);
    const int  s3 = (last3 ? p3 : p3 + 1) * kV4Pair + t;

    const int  d0 = p0 * kV4Pair + t;
    const int  d1 = p1 * kV4Pair + t;
    const int  d2 = p2 * kV4Pair + t;
    const int  d3 = p3 * kV4Pair + t;

    const float c0 = sqrtf((float)(p0 + 1));
    const float c1 = sqrtf((float)(p1 + 1));
    const float c2 = sqrtf((float)(p2 + 1));
    const float c3 = last3 ? 0.f : sqrtf((float)(p3 + 1));

    vf4 a[kPT], b[kPT];

#pragma unroll
    for (int j = 0; j < kPT; ++j)
        a[j] = __builtin_nontemporal_load(&x[s0 + j * 256]);
#pragma unroll
    for (int j = 0; j < kPT; ++j)
        b[j] = __builtin_nontemporal_load(&x[s1 + j * 256]);

#pragma unroll
    for (int j = 0; j < kPT; ++j)
        __builtin_nontemporal_store(c0 * a[j], &y[d0 + j * 256]);
#pragma unroll
    for (int j = 0; j < kPT; ++j)
        a[j] = __builtin_nontemporal_load(&x[s2 + j * 256]);

#pragma unroll
    for (int j = 0; j < kPT; ++j)
        __builtin_nontemporal_store(c1 * b[j], &y[d1 + j * 256]);
#pragma unroll
    for (int j = 0; j < kPT; ++j)
        b[j] = __builtin_nontemporal_load(&x[s3 + j * 256]);

#pragma unroll
    for (int j = 0; j < kPT; ++j)
        __builtin_nontemporal_store(c2 * a[j], &y[d2 + j * 256]);
#pragma unroll
    for (int j = 0; j < kPT; ++j)
        __builtin_nontemporal_store(c3 * b[j], &y[d3 + j * 256]);
}

extern "C" void kernel_launch(void* const* d_in, const int* in_sizes, int n_in,
                              void* d_out, int out_size, void* d_ws, size_t ws_size,
                              hipStream_t stream) {
    const vf4* x = (const vf4*)d_in[0];
    vf4* y = (vf4*)d_out;
    destroy_kernel<<<dim3(kBlocks), dim3(256), 0, stream>>>(x, y);
}